// Round 5
// baseline (1531.250 us; speedup 1.0000x reference)
//
#include <hip/hip_runtime.h>
#include <hip/hip_bf16.h>

typedef __hip_bfloat16 bf16;
typedef unsigned short u16;

// bf16 bits -> f32 (exact)
static __device__ __forceinline__ float lo16(unsigned u) { return __uint_as_float(u << 16); }
static __device__ __forceinline__ float hi16(unsigned u) { return __uint_as_float(u & 0xFFFF0000u); }
// f32 -> bf16 bits, round-to-nearest-even (no NaNs in this pipeline)
static __device__ __forceinline__ unsigned f2u(float x) {
    unsigned u = __float_as_uint(x);
    return (u + 0x7FFFu + ((u >> 16) & 1u)) >> 16;
}
static __device__ __forceinline__ unsigned pack2(float a, float b) {
    return f2u(a) | (f2u(b) << 16);
}

// ---- problem constants ----
constexpr int D0 = 240, H0 = 144, W0 = 240;
constexpr int V  = D0 * H0 * W0;          // 8,294,400 voxels
constexpr int NPIX = 480 * 640;           // 307,200 pixels
constexpr int D1 = 120, H1 = 72, W1 = 120;
constexpr int N1 = D1 * H1 * W1;          // 1,036,800
constexpr int D2 = 60, H2 = 36, W2 = 60;
constexpr int N2 = D2 * H2 * W2;          // 129,600

// Volume layout: 3 groups x [V][4] bf16 (channel ci = 4*g + c)
constexpr size_t GRP_U16  = (size_t)V * 4;                    // u16 per group
constexpr size_t GRP_BYTES = GRP_U16 * sizeof(u16);           // 66,355,200
constexpr size_t SEG_BYTES = 3 * GRP_BYTES;                   // 199,065,600
constexpr size_t WIN_BYTES = (size_t)V * sizeof(unsigned);    // 33,177,600
constexpr int ZCHUNKS  = (int)((SEG_BYTES + WIN_BYTES) / 16); // 14,515,200 uint4
constexpr int WCHUNKS  = (int)(WIN_BYTES / 16);               // 2,073,600 uint4
constexpr size_t BIG_WS = SEG_BYTES + WIN_BYTES + GRP_BYTES;  // 298,598,400

// ============================================================
// Zero-fill (uint4)
// ============================================================
__global__ void __launch_bounds__(256) kz_zero16(uint4* __restrict__ p, int nchunks) {
    int i = blockIdx.x * 256 + threadIdx.x;
    if (i >= nchunks) return;
    p[i] = make_uint4(0u, 0u, 0u, 0u);
}

// ============================================================
// Scatter: last-write-wins via winner = max(pixel_index+1)
// ============================================================
__global__ void __launch_bounds__(256) kz_scatter_win(const int* __restrict__ depth,
                                                      unsigned* __restrict__ winner) {
    int p = blockIdx.x * 256 + threadIdx.x;
    if (p >= NPIX) return;
    int d = depth[p];
    if (d > 0 && d < V) atomicMax(&winner[d], (unsigned)(p + 1));
}

__global__ void __launch_bounds__(256) kz_scatter_write(const int* __restrict__ depth,
                                                        const unsigned* __restrict__ winner,
                                                        const float* __restrict__ feat,
                                                        u16* __restrict__ seg) {
    int p = blockIdx.x * 256 + threadIdx.x;
    if (p >= NPIX) return;
    int d = depth[p];
    if (d > 0 && d < V && winner[d] == (unsigned)(p + 1)) {
#pragma unroll
        for (int g = 0; g < 3; ++g) {
            uint2 val;
            val.x = pack2(feat[(4 * g + 0) * NPIX + p], feat[(4 * g + 1) * NPIX + p]);
            val.y = pack2(feat[(4 * g + 2) * NPIX + p], feat[(4 * g + 3) * NPIX + p]);
            *(uint2*)(seg + g * GRP_U16 + (size_t)d * 4) = val;
        }
    }
}

// ============================================================
// One-pass LDS-shared avg-pool hole-fill (one group [V][4]).
// ============================================================
constexpr int FTW = 120;
constexpr int FROWS = 36;

template <bool GATED>
__global__ void __launch_bounds__(256) kz_fillL(const u16* __restrict__ rb,
                                                const unsigned* __restrict__ win,
                                                u16* __restrict__ fb) {
    __shared__ u16 S[FROWS * FTW * 4];   // 34,560 B
    int bid = blockIdx.x;                 // grid: 60*36*2 = 4320
    int wt = bid & 1;
    int t1 = bid >> 1;
    int ht = t1 % 36;
    int dt = t1 / 36;
    int d0 = dt * 4, h0 = ht * 4, w0 = wt * 120;
    int tid = threadIdx.x;

    // Phase 1: 36 rows x 60 voxel-pair tasks
    for (int tt = tid; tt < FROWS * 60; tt += 256) {
        int hr = tt / 60;
        int pt = tt - hr * 60;
        int w = w0 + 2 * pt;
        int d = d0 - 1 + hr / 6;
        int h = h0 - 1 + hr % 6;
        uint4 O = make_uint4(0u, 0u, 0u, 0u);
        if (d >= 0 && d < D0 && h >= 0 && h < H0) {
            size_t row = (size_t)(d * H0 + h) * W0;
            const u16* rp = rb + (row + w) * 4;
            uint4 X = *(const uint4*)(rp);
            if (GATED) {
                uint2 WN = *(const uint2*)(win + row + w);
                if (WN.x == 0u) { X.x = 0u; X.y = 0u; }
                if (WN.y == 0u) { X.z = 0u; X.w = 0u; }
            }
            float x0[4] = {lo16(X.x), hi16(X.x), lo16(X.y), hi16(X.y)};
            float x1[4] = {lo16(X.z), hi16(X.z), lo16(X.w), hi16(X.w)};
            float l[4] = {0.f, 0.f, 0.f, 0.f}, rr[4] = {0.f, 0.f, 0.f, 0.f};
            if (w > 0) {
                uint2 L = *(const uint2*)(rp - 4);
                if (GATED && win[row + w - 1] == 0u) { L.x = 0u; L.y = 0u; }
                l[0] = lo16(L.x); l[1] = hi16(L.x); l[2] = lo16(L.y); l[3] = hi16(L.y);
            }
            if (w < 238) {
                uint2 R = *(const uint2*)(rp + 8);
                if (GATED && win[row + w + 2] == 0u) { R.x = 0u; R.y = 0u; }
                rr[0] = lo16(R.x); rr[1] = hi16(R.x); rr[2] = lo16(R.y); rr[3] = hi16(R.y);
            }
            O.x = pack2(l[0] + x0[0] + x1[0], l[1] + x0[1] + x1[1]);
            O.y = pack2(l[2] + x0[2] + x1[2], l[3] + x0[3] + x1[3]);
            O.z = pack2(x0[0] + x1[0] + rr[0], x0[1] + x1[1] + rr[1]);
            O.w = pack2(x0[2] + x1[2] + rr[2], x0[3] + x1[3] + rr[3]);
        }
        *(uint4*)(S + ((size_t)hr * FTW + 2 * pt) * 4) = O;
    }
    __syncthreads();

    // Phase 2: 16 output rows x 60 voxel-pair tasks
    for (int ot = tid; ot < 16 * 60; ot += 256) {
        int orr = ot / 60;
        int pt = ot - orr * 60;
        int w = w0 + 2 * pt;
        int di = orr >> 2, hi_ = orr & 3;
        int d = d0 + di, h = h0 + hi_;
        float s[8] = {0.f, 0.f, 0.f, 0.f, 0.f, 0.f, 0.f, 0.f};
#pragma unroll
        for (int dd = 0; dd < 3; ++dd) {
#pragma unroll
            for (int dh = 0; dh < 3; ++dh) {
                int hr = (di + dd) * 6 + (hi_ + dh);
                uint4 T = *(const uint4*)(S + ((size_t)hr * FTW + 2 * pt) * 4);
                s[0] += lo16(T.x); s[1] += hi16(T.x); s[2] += lo16(T.y); s[3] += hi16(T.y);
                s[4] += lo16(T.z); s[5] += hi16(T.z); s[6] += lo16(T.w); s[7] += hi16(T.w);
            }
        }
        size_t row = (size_t)(d * H0 + h) * W0;
        size_t gi = (row + w) * 4;
        uint4 Rv = *(const uint4*)(rb + gi);
        if (GATED) {
            uint2 WN = *(const uint2*)(win + row + w);
            if (WN.x == 0u) { Rv.x = 0u; Rv.y = 0u; }
            if (WN.y == 0u) { Rv.z = 0u; Rv.w = 0u; }
        }
        constexpr float inv27 = 1.0f / 27.0f;
        uint4 Ov;
        Ov.x = ((Rv.x & 0x7FFFu) ? (Rv.x & 0xFFFFu) : f2u(s[0] * inv27))
             | ((((Rv.x >> 16) & 0x7FFFu) ? (Rv.x >> 16) : f2u(s[1] * inv27)) << 16);
        Ov.y = ((Rv.y & 0x7FFFu) ? (Rv.y & 0xFFFFu) : f2u(s[2] * inv27))
             | ((((Rv.y >> 16) & 0x7FFFu) ? (Rv.y >> 16) : f2u(s[3] * inv27)) << 16);
        Ov.z = ((Rv.z & 0x7FFFu) ? (Rv.z & 0xFFFFu) : f2u(s[4] * inv27))
             | ((((Rv.z >> 16) & 0x7FFFu) ? (Rv.z >> 16) : f2u(s[5] * inv27)) << 16);
        Ov.w = ((Rv.w & 0x7FFFu) ? (Rv.w & 0xFFFFu) : f2u(s[6] * inv27))
             | ((((Rv.w >> 16) & 0x7FFFu) ? (Rv.w >> 16) : f2u(s[7] * inv27)) << 16);
        *(uint4*)(fb + gi) = Ov;
    }
}

// ============================================================
// Downsample 1: conv 12->4 ++ maxpool2, relu -> x1 interleaved [N1][16]
// R18: R3's x4-pack structure (known-good 130us) with pool state
// compacted: mxp[3][4][4] (48 f32 live whole kernel) -> mxpc[4][4]
// (current group) + bf16-packed pk[3][4][2] (EXACT: pooled values are
// maxima of bf16 inputs -> bf16-representable). ~20 fewer live VGPRs
// + __launch_bounds__(256,3) pins the 3-waves/SIMD budget (<=170 VGPR)
// -> +50% occupancy for latency hiding (R3 was MLP/latency-bound).
// ============================================================
#define SEL2(ci, x0, x1) ((ci) == 0 ? lo16(x0) : (ci) == 1 ? hi16(x0) : (ci) == 2 ? lo16(x1) : hi16(x1))
// j-select from the two packed pool words
#define SELJ(j, u0, u1) ((j) == 0 ? lo16(u0) : (j) == 1 ? hi16(u0) : (j) == 2 ? lo16(u1) : hi16(u1))

__global__ void __launch_bounds__(256, 3) kz_ds1(const u16* __restrict__ f0g,
                                                 const u16* __restrict__ f1g,
                                                 const u16* __restrict__ f2g,
                                                 const float* __restrict__ w,
                                                 float* __restrict__ x1i) {
    __shared__ float wl[12 * 27 * 4];    // [ci12][tap][m] transposed
    for (int t = threadIdx.x; t < 12 * 27 * 4; t += 256) {
        int m = t & 3;
        int r = t >> 2;          // ci12*27 + tap
        int tap = r % 27;
        int ci12 = r / 27;
        wl[t] = w[(m * 12 + ci12) * 27 + tap];
    }
    __syncthreads();
    int tq = blockIdx.x * 256 + threadIdx.x;   // quad index; N1/4 = 259,200
    if (tq >= N1 / 4) return;                  // grid 1013 (one partial block)
    int q  = tq % 30;                          // quad within row, outputs 4q..4q+3
    int t2 = tq / 30;
    int ho = t2 % H1;
    int d0 = t2 / H1;
    size_t o0 = (size_t)tq * 4;                // == (d0*H1+ho)*W1 + 4q
    int vbase = 8 * q;                         // leftmost voxel of A

    const u16* bases[3] = {f0g, f1g, f2g};
    float acc[4][4];                           // [out j][m]
    unsigned pk[3][4][2];                      // [g][ci][jpair] packed relu'd pool (bf16x2)
#pragma unroll
    for (int j = 0; j < 4; ++j)
#pragma unroll
        for (int m = 0; m < 4; ++m) acc[j][m] = 0.f;

#pragma unroll
    for (int g = 0; g < 3; ++g) {
        const u16* base = bases[g];
        const float* wg = wl + g * 432;        // 4 ci x 108 floats
        float mxpc[4][4];                      // [ci][out j], current group only
#pragma unroll
        for (int ci = 0; ci < 4; ++ci)
#pragma unroll
            for (int j = 0; j < 4; ++j) mxpc[ci][j] = -1e30f;
#pragma unroll 1
        for (int kd = 0; kd < 3; ++kd) {
            int d2 = 2 * d0 - 1 + kd;
            bool dv = (d2 >= 0 && d2 < D0);
#pragma unroll
            for (int kh = 0; kh < 3; ++kh) {
                int h2 = 2 * ho - 1 + kh;
                bool vv = dv && (h2 >= 0) && (h2 < H0);
                uint2 E = make_uint2(0u, 0u);
                uint4 A = make_uint4(0u, 0u, 0u, 0u);
                uint4 B = A, C = A, D = A;
                if (vv) {
                    const u16* rp = base + ((size_t)(d2 * H0 + h2) * W0 + vbase) * 4;
                    A = *(const uint4*)(rp);          // voxels 8q, 8q+1
                    B = *(const uint4*)(rp + 8);      // voxels 8q+2, 8q+3
                    C = *(const uint4*)(rp + 16);     // voxels 8q+4, 8q+5
                    D = *(const uint4*)(rp + 24);     // voxels 8q+6, 8q+7
                    if (q > 0) E = *(const uint2*)(rp - 4);  // voxel 8q-1
                }
                const float* wk = wg + (kd * 9 + kh * 3) * 4;
#pragma unroll
                for (int ci = 0; ci < 4; ++ci) {
                    float e  = SEL2(ci, E.x, E.y);
                    float a0 = SEL2(ci, A.x, A.y), a1 = SEL2(ci, A.z, A.w);
                    float b0 = SEL2(ci, B.x, B.y), b1 = SEL2(ci, B.z, B.w);
                    float c0 = SEL2(ci, C.x, C.y), c1 = SEL2(ci, C.z, C.w);
                    float e0 = SEL2(ci, D.x, D.y), e1 = SEL2(ci, D.z, D.w);
                    const float* wp_ = wk + ci * 108;
                    float4 wA = *(const float4*)(wp_);        // kw=0, m0..3
                    float4 wB = *(const float4*)(wp_ + 4);    // kw=1
                    float4 wC = *(const float4*)(wp_ + 8);    // kw=2
                    acc[0][0] += e  * wA.x + a0 * wB.x + a1 * wC.x;
                    acc[0][1] += e  * wA.y + a0 * wB.y + a1 * wC.y;
                    acc[0][2] += e  * wA.z + a0 * wB.z + a1 * wC.z;
                    acc[0][3] += e  * wA.w + a0 * wB.w + a1 * wC.w;
                    acc[1][0] += a1 * wA.x + b0 * wB.x + b1 * wC.x;
                    acc[1][1] += a1 * wA.y + b0 * wB.y + b1 * wC.y;
                    acc[1][2] += a1 * wA.z + b0 * wB.z + b1 * wC.z;
                    acc[1][3] += a1 * wA.w + b0 * wB.w + b1 * wC.w;
                    acc[2][0] += b1 * wA.x + c0 * wB.x + c1 * wC.x;
                    acc[2][1] += b1 * wA.y + c0 * wB.y + c1 * wC.y;
                    acc[2][2] += b1 * wA.z + c0 * wB.z + c1 * wC.z;
                    acc[2][3] += b1 * wA.w + c0 * wB.w + c1 * wC.w;
                    acc[3][0] += c1 * wA.x + e0 * wB.x + e1 * wC.x;
                    acc[3][1] += c1 * wA.y + e0 * wB.y + e1 * wC.y;
                    acc[3][2] += c1 * wA.z + e0 * wB.z + e1 * wC.z;
                    acc[3][3] += c1 * wA.w + e0 * wB.w + e1 * wC.w;
                    if (kh >= 1 && kd >= 1) {   // kh compile-time; kd wave-uniform
                        mxpc[ci][0] = fmaxf(mxpc[ci][0], fmaxf(a0, a1));
                        mxpc[ci][1] = fmaxf(mxpc[ci][1], fmaxf(b0, b1));
                        mxpc[ci][2] = fmaxf(mxpc[ci][2], fmaxf(c0, c1));
                        mxpc[ci][3] = fmaxf(mxpc[ci][3], fmaxf(e0, e1));
                    }
                }
            }
        }
        // pack this group's relu'd pool maxima to bf16 pairs (exact)
#pragma unroll
        for (int ci = 0; ci < 4; ++ci) {
            pk[g][ci][0] = pack2(fmaxf(mxpc[ci][0], 0.f), fmaxf(mxpc[ci][1], 0.f));
            pk[g][ci][1] = pack2(fmaxf(mxpc[ci][2], 0.f), fmaxf(mxpc[ci][3], 0.f));
        }
    }
    // Epilogue: one contiguous 256B burst per thread (4 outputs x 64B)
#pragma unroll
    for (int j = 0; j < 4; ++j) {
        float* xo = x1i + (o0 + j) * 16;
        *(float4*)(xo) = make_float4(fmaxf(acc[j][0], 0.f), fmaxf(acc[j][1], 0.f),
                                     fmaxf(acc[j][2], 0.f), fmaxf(acc[j][3], 0.f));
#pragma unroll
        for (int g = 0; g < 3; ++g) {
            *(float4*)(xo + 4 + 4 * g) =
                make_float4(SELJ(j, pk[g][0][0], pk[g][0][1]),
                            SELJ(j, pk[g][1][0], pk[g][1][1]),
                            SELJ(j, pk[g][2][0], pk[g][2][1]),
                            SELJ(j, pk[g][3][0], pk[g][3][1]));
        }
    }
}

// ============================================================
// pw 16->4: x1 interleaved [N1][16] -> y0 interleaved [N1][4], relu
// ============================================================
__global__ void __launch_bounds__(256) kz_pw16to4i(const float* __restrict__ in,
                                                   const float* __restrict__ w,
                                                   float* __restrict__ out) {
    __shared__ float wl[64];
    if (threadIdx.x < 64) wl[threadIdx.x] = w[threadIdx.x];
    __syncthreads();
    int o = blockIdx.x * 256 + threadIdx.x;   // exact
    const float* ip = in + (size_t)o * 16;
    float4 A = *(const float4*)(ip);
    float4 B = *(const float4*)(ip + 4);
    float4 C = *(const float4*)(ip + 8);
    float4 D = *(const float4*)(ip + 12);
    float r[4];
#pragma unroll
    for (int m = 0; m < 4; ++m) {
        const float* wm = wl + m * 16;
        r[m] = A.x * wm[0] + A.y * wm[1] + A.z * wm[2] + A.w * wm[3]
             + B.x * wm[4] + B.y * wm[5] + B.z * wm[6] + B.w * wm[7]
             + C.x * wm[8] + C.y * wm[9] + C.z * wm[10] + C.w * wm[11]
             + D.x * wm[12] + D.y * wm[13] + D.z * wm[14] + D.w * wm[15];
    }
    *(float4*)(out + (size_t)o * 4) = make_float4(fmaxf(r[0], 0.f), fmaxf(r[1], 0.f),
                                                  fmaxf(r[2], 0.f), fmaxf(r[3], 0.f));
}

// ============================================================
// bconv 4ch interleaved [N1][4]: (KD,KH,KW), bias, NADD residuals, relu
// ============================================================
template <int KD, int KH, int KW, int NADD>
__global__ void __launch_bounds__(256) kz_bconv4i(const float* __restrict__ in,
                                                  const float* __restrict__ w,
                                                  const float* __restrict__ b,
                                                  const float* __restrict__ add1,
                                                  const float* __restrict__ add2,
                                                  float* __restrict__ out) {
    constexpr int S = KD * KH * KW;
    __shared__ float wl[16 * S];          // [tap][ci][m]
    __shared__ float bl[4];
    for (int t = threadIdx.x; t < 16 * S; t += 256) {
        int m = t & 3;
        int r = t >> 2;      // tap*4 + ci
        int ci = r & 3;
        int tap = r >> 2;
        wl[t] = w[(m * 4 + ci) * S + tap];
    }
    if (threadIdx.x < 4) bl[threadIdx.x] = b[threadIdx.x];
    __syncthreads();
    int o = blockIdx.x * 256 + threadIdx.x;   // exact: N1/256
    int wo = o % W1;
    int t  = o / W1;
    int ho = t % H1;
    int d0 = t / H1;
    float a0 = bl[0], a1 = bl[1], a2 = bl[2], a3 = bl[3];
#pragma unroll
    for (int kd = 0; kd < KD; ++kd) {
        int d2 = d0 + kd - KD / 2;
        if (KD > 1 && (d2 < 0 || d2 >= D1)) continue;
#pragma unroll
        for (int kh = 0; kh < KH; ++kh) {
            int h2 = ho + kh - KH / 2;
            if (KH > 1 && (h2 < 0 || h2 >= H1)) continue;
#pragma unroll
            for (int kw = 0; kw < KW; ++kw) {
                int w2 = wo + kw - KW / 2;
                if (KW > 1 && (w2 < 0 || w2 >= W1)) continue;
                float4 v = *(const float4*)(in + (size_t)((d2 * H1 + h2) * W1 + w2) * 4);
                int tap = (kd * KH + kh) * KW + kw;
                const float* wt = wl + tap * 16;
                float4 w0 = *(const float4*)(wt);
                float4 w1 = *(const float4*)(wt + 4);
                float4 w2v = *(const float4*)(wt + 8);
                float4 w3 = *(const float4*)(wt + 12);
                a0 += v.x * w0.x + v.y * w1.x + v.z * w2v.x + v.w * w3.x;
                a1 += v.x * w0.y + v.y * w1.y + v.z * w2v.y + v.w * w3.y;
                a2 += v.x * w0.z + v.y * w1.z + v.z * w2v.z + v.w * w3.z;
                a3 += v.x * w0.w + v.y * w1.w + v.z * w2v.w + v.w * w3.w;
            }
        }
    }
    if (NADD >= 1) {
        float4 r1 = *(const float4*)(add1 + (size_t)o * 4);
        a0 += r1.x; a1 += r1.y; a2 += r1.z; a3 += r1.w;
    }
    if (NADD >= 2) {
        float4 r2 = *(const float4*)(add2 + (size_t)o * 4);
        a0 += r2.x; a1 += r2.y; a2 += r2.z; a3 += r2.w;
    }
    *(float4*)(out + (size_t)o * 4) = make_float4(fmaxf(a0, 0.f), fmaxf(a1, 0.f),
                                                  fmaxf(a2, 0.f), fmaxf(a3, 0.f));
}

// ============================================================
// FUSED: bconv4 (3,1,3) + bias + 2 residuals + relu -> pw 4->16
//        + residual(x1i) + relu -> x1b PLANAR [16][N1]
// ============================================================
__global__ void __launch_bounds__(256) kz_bconv4i_pw(const float* __restrict__ in,
                                                     const float* __restrict__ w,
                                                     const float* __restrict__ b,
                                                     const float* __restrict__ add1,
                                                     const float* __restrict__ add2,
                                                     const float* __restrict__ wp,
                                                     const float* __restrict__ x1i,
                                                     float* __restrict__ out) {
    constexpr int S = 9;   // 3*1*3
    __shared__ float wl[16 * S];          // [tap][ci][m]
    __shared__ float bl[4];
    __shared__ float wpl[64];
    for (int t = threadIdx.x; t < 16 * S; t += 256) {
        int m = t & 3;
        int r = t >> 2;
        int ci = r & 3;
        int tap = r >> 2;
        wl[t] = w[(m * 4 + ci) * S + tap];
    }
    if (threadIdx.x < 4) bl[threadIdx.x] = b[threadIdx.x];
    if (threadIdx.x < 64) wpl[threadIdx.x] = wp[threadIdx.x];
    __syncthreads();
    int o = blockIdx.x * 256 + threadIdx.x;   // exact
    int wo = o % W1;
    int t  = o / W1;
    int ho = t % H1;
    int d0 = t / H1;
    float a0 = bl[0], a1 = bl[1], a2 = bl[2], a3 = bl[3];
#pragma unroll
    for (int kd = 0; kd < 3; ++kd) {
        int d2 = d0 + kd - 1;
        if (d2 < 0 || d2 >= D1) continue;
#pragma unroll
        for (int kw = 0; kw < 3; ++kw) {
            int w2 = wo + kw - 1;
            if (w2 < 0 || w2 >= W1) continue;
            float4 v = *(const float4*)(in + (size_t)((d2 * H1 + ho) * W1 + w2) * 4);
            int tap = kd * 3 + kw;
            const float* wt = wl + tap * 16;
            float4 w0 = *(const float4*)(wt);
            float4 w1 = *(const float4*)(wt + 4);
            float4 w2v = *(const float4*)(wt + 8);
            float4 w3 = *(const float4*)(wt + 12);
            a0 += v.x * w0.x + v.y * w1.x + v.z * w2v.x + v.w * w3.x;
            a1 += v.x * w0.y + v.y * w1.y + v.z * w2v.y + v.w * w3.y;
            a2 += v.x * w0.z + v.y * w1.z + v.z * w2v.z + v.w * w3.z;
            a3 += v.x * w0.w + v.y * w1.w + v.z * w2v.w + v.w * w3.w;
        }
    }
    float4 r1 = *(const float4*)(add1 + (size_t)o * 4);
    float4 r2 = *(const float4*)(add2 + (size_t)o * 4);
    float y0 = fmaxf(a0 + r1.x + r2.x, 0.f);
    float y1 = fmaxf(a1 + r1.y + r2.y, 0.f);
    float y2 = fmaxf(a2 + r1.z + r2.z, 0.f);
    float y3 = fmaxf(a3 + r1.w + r2.w, 0.f);
    const float* rp = x1i + (size_t)o * 16;
    float4 R0 = *(const float4*)(rp);
    float4 R1 = *(const float4*)(rp + 4);
    float4 R2 = *(const float4*)(rp + 8);
    float4 R3 = *(const float4*)(rp + 12);
    float rr[16] = {R0.x, R0.y, R0.z, R0.w, R1.x, R1.y, R1.z, R1.w,
                    R2.x, R2.y, R2.z, R2.w, R3.x, R3.y, R3.z, R3.w};
#pragma unroll
    for (int m = 0; m < 16; ++m) {
        const float* wm = wpl + m * 4;
        float r = y0 * wm[0] + y1 * wm[1] + y2 * wm[2] + y3 * wm[3] + rr[m];
        out[(size_t)m * N1 + o] = fmaxf(r, 0.f);
    }
}

// ============================================================
// FUSED Downsample 2 + pw 32->8
// ============================================================
__global__ void __launch_bounds__(256) kz_ds2f(const float* __restrict__ in,
                                               const float* __restrict__ w,
                                               const float* __restrict__ wz,
                                               float* __restrict__ out,
                                               float* __restrict__ z0i) {
    __shared__ float wl[16 * 27 * 16];    // [ci][tap][m] transposed, 27648 B
    __shared__ float wzl[256];            // [k][m] transposed
    for (int t = threadIdx.x; t < 16 * 27 * 16; t += 256) {
        int m = t & 15;
        int r = t >> 4;          // ci*27 + tap
        int tap = r % 27;
        int ci = r / 27;
        wl[t] = w[(m * 16 + ci) * 27 + tap];
    }
    if (threadIdx.x < 256) {
        int m = threadIdx.x & 7;
        int k = threadIdx.x >> 3;
        wzl[threadIdx.x] = wz[m * 32 + k];
    }
    __syncthreads();
    int o = blockIdx.x * 256 + threadIdx.x;
    if (o >= N2) return;
    int wo = o % W2;
    int t  = o / W2;
    int ho = t % H2;
    int d0 = t / H2;
    float acc[16];
    float zacc[8];
#pragma unroll
    for (int m = 0; m < 16; ++m) acc[m] = 0.f;
#pragma unroll
    for (int m = 0; m < 8; ++m) zacc[m] = 0.f;
#pragma unroll 1
    for (int ci = 0; ci < 16; ++ci) {
        const float* base = in + ci * N1;
        const float* wci = wl + ci * 432;   // 27*16
        float mx = -1e30f;
#pragma unroll 1
        for (int kd = 0; kd < 3; ++kd) {
            int d2 = 2 * d0 - 1 + kd;
            bool dv = (d2 >= 0 && d2 < D1);
#pragma unroll
            for (int kh = 0; kh < 3; ++kh) {
                int h2 = 2 * ho - 1 + kh;
                bool rvv = dv && (h2 >= 0 && h2 < H1);
                float vm1 = 0.f, v0 = 0.f, v1 = 0.f;
                if (rvv) {
                    int r2 = (d2 * H1 + h2) * W1 + 2 * wo;
                    float2 pb = *(const float2*)(base + r2);
                    v0 = pb.x; v1 = pb.y;
                    if (wo > 0) {
                        float2 pa = *(const float2*)(base + r2 - 2);
                        vm1 = pa.y;
                    }
                }
                const float* wk = wci + (kd * 9 + kh * 3) * 16;
#pragma unroll
                for (int q = 0; q < 4; ++q) {
                    float4 wA = *(const float4*)(wk + q * 4);        // kw=0
                    float4 wB = *(const float4*)(wk + 16 + q * 4);   // kw=1
                    float4 wC = *(const float4*)(wk + 32 + q * 4);   // kw=2
                    acc[4 * q + 0] += vm1 * wA.x + v0 * wB.x + v1 * wC.x;
                    acc[4 * q + 1] += vm1 * wA.y + v0 * wB.y + v1 * wC.y;
                    acc[4 * q + 2] += vm1 * wA.z + v0 * wB.z + v1 * wC.z;
                    acc[4 * q + 3] += vm1 * wA.w + v0 * wB.w + v1 * wC.w;
                }
                if (kd >= 1 && kh >= 1) mx = fmaxf(mx, fmaxf(v0, v1));
            }
        }
        float pl = fmaxf(mx, 0.f);
        out[(16 + ci) * N2 + o] = pl;
        {
            const float* wq = wzl + (16 + ci) * 8;
            float4 z0 = *(const float4*)(wq);
            float4 z1 = *(const float4*)(wq + 4);
            zacc[0] += z0.x * pl; zacc[1] += z0.y * pl; zacc[2] += z0.z * pl; zacc[3] += z0.w * pl;
            zacc[4] += z1.x * pl; zacc[5] += z1.y * pl; zacc[6] += z1.z * pl; zacc[7] += z1.w * pl;
        }
    }
#pragma unroll
    for (int j = 0; j < 16; ++j) {
        float cj = fmaxf(acc[j], 0.f);
        out[j * N2 + o] = cj;
        const float* wq = wzl + j * 8;
        float4 z0 = *(const float4*)(wq);
        float4 z1 = *(const float4*)(wq + 4);
        zacc[0] += z0.x * cj; zacc[1] += z0.y * cj; zacc[2] += z0.z * cj; zacc[3] += z0.w * cj;
        zacc[4] += z1.x * cj; zacc[5] += z1.y * cj; zacc[6] += z1.z * cj; zacc[7] += z1.w * cj;
    }
    float* op = z0i + (size_t)o * 8;
    *(float4*)(op)     = make_float4(fmaxf(zacc[0], 0.f), fmaxf(zacc[1], 0.f),
                                     fmaxf(zacc[2], 0.f), fmaxf(zacc[3], 0.f));
    *(float4*)(op + 4) = make_float4(fmaxf(zacc[4], 0.f), fmaxf(zacc[5], 0.f),
                                     fmaxf(zacc[6], 0.f), fmaxf(zacc[7], 0.f));
}

// ============================================================
// bconv 8ch interleaved [N2][8]
// ============================================================
template <int KD, int KH, int KW, int NADD>
__global__ void __launch_bounds__(256) kz_bconv8i(const float* __restrict__ in,
                                                  const float* __restrict__ w,
                                                  const float* __restrict__ b,
                                                  const float* __restrict__ add1,
                                                  const float* __restrict__ add2,
                                                  float* __restrict__ out) {
    constexpr int S = KD * KH * KW;
    __shared__ float wl[64 * S];          // [tap][ci][m]
    __shared__ float bl[8];
    for (int t = threadIdx.x; t < 64 * S; t += 256) {
        int m = t & 7;
        int r = t >> 3;      // tap*8 + ci
        int ci = r & 7;
        int tap = r >> 3;
        wl[t] = w[(m * 8 + ci) * S + tap];
    }
    if (threadIdx.x < 8) bl[threadIdx.x] = b[threadIdx.x];
    __syncthreads();
    int o = blockIdx.x * 256 + threadIdx.x;
    if (o >= N2) return;
    int wo = o % W2;
    int t  = o / W2;
    int ho = t % H2;
    int d0 = t / H2;
    float acc[8];
#pragma unroll
    for (int m = 0; m < 8; ++m) acc[m] = bl[m];
#pragma unroll
    for (int kd = 0; kd < KD; ++kd) {
        int d2 = d0 + kd - KD / 2;
        if (KD > 1 && (d2 < 0 || d2 >= D2)) continue;
#pragma unroll
        for (int kh = 0; kh < KH; ++kh) {
            int h2 = ho + kh - KH / 2;
            if (KH > 1 && (h2 < 0 || h2 >= H2)) continue;
#pragma unroll
            for (int kw = 0; kw < KW; ++kw) {
                int w2 = wo + kw - KW / 2;
                if (KW > 1 && (w2 < 0 || w2 >= W2)) continue;
                const float* vp = in + (size_t)((d2 * H2 + h2) * W2 + w2) * 8;
                float4 v0 = *(const float4*)(vp);
                float4 v1 = *(const float4*)(vp + 4);
                float vv[8] = {v0.x, v0.y, v0.z, v0.w, v1.x, v1.y, v1.z, v1.w};
                int tap = (kd * KH + kh) * KW + kw;
                const float* wt = wl + tap * 64;
#pragma unroll
                for (int ci = 0; ci < 8; ++ci) {
                    float vc = vv[ci];
                    float4 wa = *(const float4*)(wt + ci * 8);
                    float4 wb = *(const float4*)(wt + ci * 8 + 4);
                    acc[0] += vc * wa.x; acc[1] += vc * wa.y;
                    acc[2] += vc * wa.z; acc[3] += vc * wa.w;
                    acc[4] += vc * wb.x; acc[5] += vc * wb.y;
                    acc[6] += vc * wb.z; acc[7] += vc * wb.w;
                }
            }
        }
    }
    if (NADD >= 1) {
        const float* ap = add1 + (size_t)o * 8;
        float4 r0 = *(const float4*)(ap), r1 = *(const float4*)(ap + 4);
        acc[0] += r0.x; acc[1] += r0.y; acc[2] += r0.z; acc[3] += r0.w;
        acc[4] += r1.x; acc[5] += r1.y; acc[6] += r1.z; acc[7] += r1.w;
    }
    if (NADD >= 2) {
        const float* ap = add2 + (size_t)o * 8;
        float4 r0 = *(const float4*)(ap), r1 = *(const float4*)(ap + 4);
        acc[0] += r0.x; acc[1] += r0.y; acc[2] += r0.z; acc[3] += r0.w;
        acc[4] += r1.x; acc[5] += r1.y; acc[6] += r1.z; acc[7] += r1.w;
    }
    float* op = out + (size_t)o * 8;
    *(float4*)(op)     = make_float4(fmaxf(acc[0], 0.f), fmaxf(acc[1], 0.f),
                                     fmaxf(acc[2], 0.f), fmaxf(acc[3], 0.f));
    *(float4*)(op + 4) = make_float4(fmaxf(acc[4], 0.f), fmaxf(acc[5], 0.f),
                                     fmaxf(acc[6], 0.f), fmaxf(acc[7], 0.f));
}

// ============================================================
// FUSED: bconv8 (3,1,3) + residuals + relu -> pw 8->32 + residual + relu
// -> d_out planar [32][N2]
// ============================================================
__global__ void __launch_bounds__(256) kz_bconv8i_pw(const float* __restrict__ in,
                                                     const float* __restrict__ w,
                                                     const float* __restrict__ b,
                                                     const float* __restrict__ add1,
                                                     const float* __restrict__ add2,
                                                     const float* __restrict__ wp,
                                                     const float* __restrict__ resp,
                                                     float* __restrict__ out) {
    constexpr int S = 9;   // 3*1*3
    __shared__ float wl[64 * S];          // [tap][ci][m]
    __shared__ float bl[8];
    __shared__ float wpl[256];
    for (int t = threadIdx.x; t < 64 * S; t += 256) {
        int m = t & 7;
        int r = t >> 3;
        int ci = r & 7;
        int tap = r >> 3;
        wl[t] = w[(m * 8 + ci) * S + tap];
    }
    if (threadIdx.x < 8) bl[threadIdx.x] = b[threadIdx.x];
    if (threadIdx.x < 256) wpl[threadIdx.x] = wp[threadIdx.x];
    __syncthreads();
    int o = blockIdx.x * 256 + threadIdx.x;
    if (o >= N2) return;
    int wo = o % W2;
    int t  = o / W2;
    int ho = t % H2;
    int d0 = t / H2;
    float acc[8];
#pragma unroll
    for (int m = 0; m < 8; ++m) acc[m] = bl[m];
#pragma unroll
    for (int kd = 0; kd < 3; ++kd) {
        int d2 = d0 + kd - 1;
        if (d2 < 0 || d2 >= D2) continue;
#pragma unroll
        for (int kw = 0; kw < 3; ++kw) {
            int w2 = wo + kw - 1;
            if (w2 < 0 || w2 >= W2) continue;
            const float* vp = in + (size_t)((d2 * H2 + ho) * W2 + w2) * 8;
            float4 v0 = *(const float4*)(vp);
            float4 v1 = *(const float4*)(vp + 4);
            float vv[8] = {v0.x, v0.y, v0.z, v0.w, v1.x, v1.y, v1.z, v1.w};
            int tap = kd * 3 + kw;
            const float* wt = wl + tap * 64;
#pragma unroll
            for (int ci = 0; ci < 8; ++ci) {
                float vc = vv[ci];
                float4 wa = *(const float4*)(wt + ci * 8);
                float4 wb = *(const float4*)(wt + ci * 8 + 4);
                acc[0] += vc * wa.x; acc[1] += vc * wa.y;
                acc[2] += vc * wa.z; acc[3] += vc * wa.w;
                acc[4] += vc * wb.x; acc[5] += vc * wb.y;
                acc[6] += vc * wb.z; acc[7] += vc * wb.w;
            }
        }
    }
    {
        const float* ap = add1 + (size_t)o * 8;
        float4 r0 = *(const float4*)(ap), r1 = *(const float4*)(ap + 4);
        acc[0] += r0.x; acc[1] += r0.y; acc[2] += r0.z; acc[3] += r0.w;
        acc[4] += r1.x; acc[5] += r1.y; acc[6] += r1.z; acc[7] += r1.w;
    }
    {
        const float* ap = add2 + (size_t)o * 8;
        float4 r0 = *(const float4*)(ap), r1 = *(const float4*)(ap + 4);
        acc[0] += r0.x; acc[1] += r0.y; acc[2] += r0.z; acc[3] += r0.w;
        acc[4] += r1.x; acc[5] += r1.y; acc[6] += r1.z; acc[7] += r1.w;
    }
#pragma unroll
    for (int m = 0; m < 8; ++m) acc[m] = fmaxf(acc[m], 0.f);
#pragma unroll
    for (int m = 0; m < 32; ++m) {
        const float* wm = wpl + m * 8;
        float r = acc[0] * wm[0] + acc[1] * wm[1] + acc[2] * wm[2] + acc[3] * wm[3]
                + acc[4] * wm[4] + acc[5] * wm[5] + acc[6] * wm[6] + acc[7] * wm[7];
        r += resp[(size_t)m * N2 + o];
        out[(size_t)m * N2 + o] = fmaxf(r, 0.f);
    }
}

// ============================================================
extern "C" void kernel_launch(void* const* d_in, const int* in_sizes, int n_in,
                              void* d_out, int out_size, void* d_ws, size_t ws_size,
                              hipStream_t stream) {
    const float* feat   = (const float*)d_in[0];
    const int*   depth  = (const int*)d_in[1];
    const float* w_ds1  = (const float*)d_in[2];
    const float* b1_win = (const float*)d_in[3];
    const float* b1w133 = (const float*)d_in[4];
    const float* b1b133 = (const float*)d_in[5];
    const float* b1w331 = (const float*)d_in[6];
    const float* b1b331 = (const float*)d_in[7];
    const float* b1w313 = (const float*)d_in[8];
    const float* b1b313 = (const float*)d_in[9];
    const float* b1wout = (const float*)d_in[10];
    const float* w_ds2  = (const float*)d_in[11];
    const float* b2_win = (const float*)d_in[12];
    const float* b2w133 = (const float*)d_in[13];
    const float* b2b133 = (const float*)d_in[14];
    const float* b2w331 = (const float*)d_in[15];
    const float* b2b331 = (const float*)d_in[16];
    const float* b2w313 = (const float*)d_in[17];
    const float* b2b313 = (const float*)d_in[18];
    const float* b2wout = (const float*)d_in[19];

    char* base = (char*)d_ws;
    // Branch once on ws_size (deterministic every call -> graph-safe).
    const bool bigws = (ws_size >= BIG_WS);

    // --- Region layout ---
    u16* raw0 = (u16*)base;                               // [0, 66.35)
    u16* raw1 = (u16*)(base + GRP_BYTES);                 // [66.35, 132.7)
    u16* raw2 = (u16*)(base + 2 * GRP_BYTES);             // [132.7, 199.07)
    unsigned* winner = (unsigned*)(base + SEG_BYTES);     // [199.07, 232.25)
    u16* fil0 = bigws ? (u16*)(base + SEG_BYTES + WIN_BYTES) : (u16*)(base + SEG_BYTES);
    u16* fil1 = (u16*)base;                               // [0, 66.35)   after raw0 dies
    u16* fil2 = (u16*)(base + GRP_BYTES);                 // [66.35,132.7) after raw1 dies
    float* x1i = (float*)(base + 2 * GRP_BYTES);          // [132.7,199.07) after raw2 dies
    float* y0i = (float*)base;                            // after fil1/fil2 die (post-ds1)
    float* y1i = y0i + 4 * N1;
    float* y2i = y1i + 4 * N1;
    float* x1b = (float*)(base + SEG_BYTES);              // [199.07,265.4) (winner+fil0 dead)
    float* x2  = (float*)base;                            // after y dead
    float* z0i = x2 + 32 * N2;
    float* z1i = z0i + 8 * N2;
    float* z2i = z1i + 8 * N2;

    float* out = (float*)d_out;   // reference output dtype is float32

    // 1. zero
    if (bigws) {
        kz_zero16<<<WCHUNKS / 256, 256, 0, stream>>>((uint4*)winner, WCHUNKS);
    } else {
        kz_zero16<<<ZCHUNKS / 256, 256, 0, stream>>>((uint4*)base, ZCHUNKS);
    }

    // 2. deterministic last-write-wins scatter
    kz_scatter_win  <<<NPIX / 256, 256, 0, stream>>>(depth, winner);
    kz_scatter_write<<<NPIX / 256, 256, 0, stream>>>(depth, winner, feat, raw0);

    // 3. one-pass LDS-shared hole-fill, per group, out-of-place (rotating)
    if (bigws) {
        kz_fillL<true><<<4320, 256, 0, stream>>>(raw0, winner, fil0);
        kz_fillL<true><<<4320, 256, 0, stream>>>(raw1, winner, fil1);
        kz_fillL<true><<<4320, 256, 0, stream>>>(raw2, winner, fil2);
    } else {
        kz_fillL<false><<<4320, 256, 0, stream>>>(raw0, nullptr, fil0);
        kz_fillL<false><<<4320, 256, 0, stream>>>(raw1, nullptr, fil1);
        kz_fillL<false><<<4320, 256, 0, stream>>>(raw2, nullptr, fil2);
    }

    // 4. downsample 1 (W-pack x4, packed pool, 3 waves/SIMD) -> x1 interleaved [N1][16]
    kz_ds1<<<(N1 / 4 + 255) / 256, 256, 0, stream>>>(fil0, fil1, fil2, w_ds1, x1i);

    // 5. bottleneck 1 (interleaved [N1][4]); last bconv fused with pw4->16
    kz_pw16to4i<<<N1 / 256, 256, 0, stream>>>(x1i, b1_win, y0i);
    kz_bconv4i<1, 3, 3, 0><<<N1 / 256, 256, 0, stream>>>(y0i, b1w133, b1b133, nullptr, nullptr, y1i);
    kz_bconv4i<3, 3, 1, 1><<<N1 / 256, 256, 0, stream>>>(y1i, b1w331, b1b331, y1i, nullptr, y2i);
    kz_bconv4i_pw<<<N1 / 256, 256, 0, stream>>>(y2i, b1w313, b1b313, y2i, y1i, b1wout, x1i, x1b);

    // 6. downsample 2 fused with pw32->8 -> x2 planar + z0 interleaved
    kz_ds2f<<<(N2 + 255) / 256, 256, 0, stream>>>(x1b, w_ds2, b2_win, x2, z0i);

    // 7. bottleneck 2 (interleaved [N2][8]); last bconv fused with pw8->32
    kz_bconv8i<1, 3, 3, 0><<<(N2 + 255) / 256, 256, 0, stream>>>(z0i, b2w133, b2b133, nullptr, nullptr, z1i);
    kz_bconv8i<3, 3, 1, 1><<<(N2 + 255) / 256, 256, 0, stream>>>(z1i, b2w331, b2b331, z1i, nullptr, z2i);
    kz_bconv8i_pw<<<(N2 + 255) / 256, 256, 0, stream>>>(z2i, b2w313, b2b313, z2i, z1i, b2wout, x2, out);

    (void)in_sizes; (void)n_in; (void)out_size;
}

// Round 6
// 646.640 us; speedup vs baseline: 2.3680x; 2.3680x over previous
//
#include <hip/hip_runtime.h>
#include <hip/hip_bf16.h>

typedef __hip_bfloat16 bf16;
typedef unsigned short u16;

// bf16 bits -> f32 (exact)
static __device__ __forceinline__ float lo16(unsigned u) { return __uint_as_float(u << 16); }
static __device__ __forceinline__ float hi16(unsigned u) { return __uint_as_float(u & 0xFFFF0000u); }
// f32 -> bf16 bits, round-to-nearest-even (no NaNs in this pipeline)
static __device__ __forceinline__ unsigned f2u(float x) {
    unsigned u = __float_as_uint(x);
    return (u + 0x7FFFu + ((u >> 16) & 1u)) >> 16;
}
static __device__ __forceinline__ unsigned pack2(float a, float b) {
    return f2u(a) | (f2u(b) << 16);
}

// ---- problem constants ----
constexpr int D0 = 240, H0 = 144, W0 = 240;
constexpr int V  = D0 * H0 * W0;          // 8,294,400 voxels
constexpr int NPIX = 480 * 640;           // 307,200 pixels
constexpr int D1 = 120, H1 = 72, W1 = 120;
constexpr int N1 = D1 * H1 * W1;          // 1,036,800
constexpr int D2 = 60, H2 = 36, W2 = 60;
constexpr int N2 = D2 * H2 * W2;          // 129,600

// Volume layout: 3 groups x [V][4] bf16 (channel ci = 4*g + c)
constexpr size_t GRP_U16  = (size_t)V * 4;                    // u16 per group
constexpr size_t GRP_BYTES = GRP_U16 * sizeof(u16);           // 66,355,200
constexpr size_t SEG_BYTES = 3 * GRP_BYTES;                   // 199,065,600
constexpr size_t WIN_BYTES = (size_t)V * sizeof(unsigned);    // 33,177,600
constexpr int ZCHUNKS  = (int)((SEG_BYTES + WIN_BYTES) / 16); // 14,515,200 uint4
constexpr int WCHUNKS  = (int)(WIN_BYTES / 16);               // 2,073,600 uint4
constexpr size_t BIG_WS = SEG_BYTES + WIN_BYTES + GRP_BYTES;  // 298,598,400

// ============================================================
// Zero-fill (uint4)
// ============================================================
__global__ void __launch_bounds__(256) kz_zero16(uint4* __restrict__ p, int nchunks) {
    int i = blockIdx.x * 256 + threadIdx.x;
    if (i >= nchunks) return;
    p[i] = make_uint4(0u, 0u, 0u, 0u);
}

// ============================================================
// Scatter: last-write-wins via winner = max(pixel_index+1)
// ============================================================
__global__ void __launch_bounds__(256) kz_scatter_win(const int* __restrict__ depth,
                                                      unsigned* __restrict__ winner) {
    int p = blockIdx.x * 256 + threadIdx.x;
    if (p >= NPIX) return;
    int d = depth[p];
    if (d > 0 && d < V) atomicMax(&winner[d], (unsigned)(p + 1));
}

__global__ void __launch_bounds__(256) kz_scatter_write(const int* __restrict__ depth,
                                                        const unsigned* __restrict__ winner,
                                                        const float* __restrict__ feat,
                                                        u16* __restrict__ seg) {
    int p = blockIdx.x * 256 + threadIdx.x;
    if (p >= NPIX) return;
    int d = depth[p];
    if (d > 0 && d < V && winner[d] == (unsigned)(p + 1)) {
#pragma unroll
        for (int g = 0; g < 3; ++g) {
            uint2 val;
            val.x = pack2(feat[(4 * g + 0) * NPIX + p], feat[(4 * g + 1) * NPIX + p]);
            val.y = pack2(feat[(4 * g + 2) * NPIX + p], feat[(4 * g + 3) * NPIX + p]);
            *(uint2*)(seg + g * GRP_U16 + (size_t)d * 4) = val;
        }
    }
}

// ============================================================
// One-pass LDS-shared avg-pool hole-fill (one group [V][4]).
// ============================================================
constexpr int FTW = 120;
constexpr int FROWS = 36;

template <bool GATED>
__global__ void __launch_bounds__(256) kz_fillL(const u16* __restrict__ rb,
                                                const unsigned* __restrict__ win,
                                                u16* __restrict__ fb) {
    __shared__ u16 S[FROWS * FTW * 4];   // 34,560 B
    int bid = blockIdx.x;                 // grid: 60*36*2 = 4320
    int wt = bid & 1;
    int t1 = bid >> 1;
    int ht = t1 % 36;
    int dt = t1 / 36;
    int d0 = dt * 4, h0 = ht * 4, w0 = wt * 120;
    int tid = threadIdx.x;

    // Phase 1: 36 rows x 60 voxel-pair tasks
    for (int tt = tid; tt < FROWS * 60; tt += 256) {
        int hr = tt / 60;
        int pt = tt - hr * 60;
        int w = w0 + 2 * pt;
        int d = d0 - 1 + hr / 6;
        int h = h0 - 1 + hr % 6;
        uint4 O = make_uint4(0u, 0u, 0u, 0u);
        if (d >= 0 && d < D0 && h >= 0 && h < H0) {
            size_t row = (size_t)(d * H0 + h) * W0;
            const u16* rp = rb + (row + w) * 4;
            uint4 X = *(const uint4*)(rp);
            if (GATED) {
                uint2 WN = *(const uint2*)(win + row + w);
                if (WN.x == 0u) { X.x = 0u; X.y = 0u; }
                if (WN.y == 0u) { X.z = 0u; X.w = 0u; }
            }
            float x0[4] = {lo16(X.x), hi16(X.x), lo16(X.y), hi16(X.y)};
            float x1[4] = {lo16(X.z), hi16(X.z), lo16(X.w), hi16(X.w)};
            float l[4] = {0.f, 0.f, 0.f, 0.f}, rr[4] = {0.f, 0.f, 0.f, 0.f};
            if (w > 0) {
                uint2 L = *(const uint2*)(rp - 4);
                if (GATED && win[row + w - 1] == 0u) { L.x = 0u; L.y = 0u; }
                l[0] = lo16(L.x); l[1] = hi16(L.x); l[2] = lo16(L.y); l[3] = hi16(L.y);
            }
            if (w < 238) {
                uint2 R = *(const uint2*)(rp + 8);
                if (GATED && win[row + w + 2] == 0u) { R.x = 0u; R.y = 0u; }
                rr[0] = lo16(R.x); rr[1] = hi16(R.x); rr[2] = lo16(R.y); rr[3] = hi16(R.y);
            }
            O.x = pack2(l[0] + x0[0] + x1[0], l[1] + x0[1] + x1[1]);
            O.y = pack2(l[2] + x0[2] + x1[2], l[3] + x0[3] + x1[3]);
            O.z = pack2(x0[0] + x1[0] + rr[0], x0[1] + x1[1] + rr[1]);
            O.w = pack2(x0[2] + x1[2] + rr[2], x0[3] + x1[3] + rr[3]);
        }
        *(uint4*)(S + ((size_t)hr * FTW + 2 * pt) * 4) = O;
    }
    __syncthreads();

    // Phase 2: 16 output rows x 60 voxel-pair tasks
    for (int ot = tid; ot < 16 * 60; ot += 256) {
        int orr = ot / 60;
        int pt = ot - orr * 60;
        int w = w0 + 2 * pt;
        int di = orr >> 2, hi_ = orr & 3;
        int d = d0 + di, h = h0 + hi_;
        float s[8] = {0.f, 0.f, 0.f, 0.f, 0.f, 0.f, 0.f, 0.f};
#pragma unroll
        for (int dd = 0; dd < 3; ++dd) {
#pragma unroll
            for (int dh = 0; dh < 3; ++dh) {
                int hr = (di + dd) * 6 + (hi_ + dh);
                uint4 T = *(const uint4*)(S + ((size_t)hr * FTW + 2 * pt) * 4);
                s[0] += lo16(T.x); s[1] += hi16(T.x); s[2] += lo16(T.y); s[3] += hi16(T.y);
                s[4] += lo16(T.z); s[5] += hi16(T.z); s[6] += lo16(T.w); s[7] += hi16(T.w);
            }
        }
        size_t row = (size_t)(d * H0 + h) * W0;
        size_t gi = (row + w) * 4;
        uint4 Rv = *(const uint4*)(rb + gi);
        if (GATED) {
            uint2 WN = *(const uint2*)(win + row + w);
            if (WN.x == 0u) { Rv.x = 0u; Rv.y = 0u; }
            if (WN.y == 0u) { Rv.z = 0u; Rv.w = 0u; }
        }
        constexpr float inv27 = 1.0f / 27.0f;
        uint4 Ov;
        Ov.x = ((Rv.x & 0x7FFFu) ? (Rv.x & 0xFFFFu) : f2u(s[0] * inv27))
             | ((((Rv.x >> 16) & 0x7FFFu) ? (Rv.x >> 16) : f2u(s[1] * inv27)) << 16);
        Ov.y = ((Rv.y & 0x7FFFu) ? (Rv.y & 0xFFFFu) : f2u(s[2] * inv27))
             | ((((Rv.y >> 16) & 0x7FFFu) ? (Rv.y >> 16) : f2u(s[3] * inv27)) << 16);
        Ov.z = ((Rv.z & 0x7FFFu) ? (Rv.z & 0xFFFFu) : f2u(s[4] * inv27))
             | ((((Rv.z >> 16) & 0x7FFFu) ? (Rv.z >> 16) : f2u(s[5] * inv27)) << 16);
        Ov.w = ((Rv.w & 0x7FFFu) ? (Rv.w & 0xFFFFu) : f2u(s[6] * inv27))
             | ((((Rv.w >> 16) & 0x7FFFu) ? (Rv.w >> 16) : f2u(s[7] * inv27)) << 16);
        *(uint4*)(fb + gi) = Ov;
    }
}

// ============================================================
// Downsample 1: conv 12->4 ++ maxpool2, relu -> x1 interleaved [N1][16]
// R16/R3 body (measured 130us, VGPR 180 — the proven local optimum; R4/R5
// showed both more per-thread buffering and forced occupancy spill).
// R19: optional FUSED pw16->4 epilogue (FUSE_PW): all 16 x1 channels are
// already in registers at the end, so y0 = relu(W_in . x1) costs 64 LDS
// floats + 64 FMA/output and deletes the separate 83MB pw kernel.
// ============================================================
#define SEL2(ci, x0, x1) ((ci) == 0 ? lo16(x0) : (ci) == 1 ? hi16(x0) : (ci) == 2 ? lo16(x1) : hi16(x1))

template <bool FUSE_PW>
__global__ void __launch_bounds__(256) kz_ds1(const u16* __restrict__ f0g,
                                              const u16* __restrict__ f1g,
                                              const u16* __restrict__ f2g,
                                              const float* __restrict__ w,
                                              const float* __restrict__ wpw,
                                              float* __restrict__ x1i,
                                              float* __restrict__ y0o) {
    __shared__ float wl[12 * 27 * 4];    // [ci12][tap][m] transposed
    __shared__ float wpl[64];            // pw 16->4 table (FUSE_PW only)
    for (int t = threadIdx.x; t < 12 * 27 * 4; t += 256) {
        int m = t & 3;
        int r = t >> 2;          // ci12*27 + tap
        int tap = r % 27;
        int ci12 = r / 27;
        wl[t] = w[(m * 12 + ci12) * 27 + tap];
    }
    if (FUSE_PW && threadIdx.x < 64) wpl[threadIdx.x] = wpw[threadIdx.x];
    __syncthreads();
    int tq = blockIdx.x * 256 + threadIdx.x;   // quad index; N1/4 = 259,200
    if (tq >= N1 / 4) return;                  // grid 1013 (one partial block)
    int q  = tq % 30;                          // quad within row, outputs 4q..4q+3
    int t2 = tq / 30;
    int ho = t2 % H1;
    int d0 = t2 / H1;
    size_t o0 = (size_t)tq * 4;                // == (d0*H1+ho)*W1 + 4q
    int vbase = 8 * q;                         // leftmost voxel of A

    const u16* bases[3] = {f0g, f1g, f2g};
    float acc[4][4];                           // [out j][m]
    float mxp[3][4][4];                        // [g][ci][out j] -- all static idx
#pragma unroll
    for (int j = 0; j < 4; ++j)
#pragma unroll
        for (int m = 0; m < 4; ++m) acc[j][m] = 0.f;
#pragma unroll
    for (int g = 0; g < 3; ++g)
#pragma unroll
        for (int ci = 0; ci < 4; ++ci)
#pragma unroll
            for (int j = 0; j < 4; ++j) mxp[g][ci][j] = -1e30f;

#pragma unroll
    for (int g = 0; g < 3; ++g) {
        const u16* base = bases[g];
        const float* wg = wl + g * 432;        // 4 ci x 108 floats
#pragma unroll 1
        for (int kd = 0; kd < 3; ++kd) {
            int d2 = 2 * d0 - 1 + kd;
            bool dv = (d2 >= 0 && d2 < D0);
#pragma unroll
            for (int kh = 0; kh < 3; ++kh) {
                int h2 = 2 * ho - 1 + kh;
                bool vv = dv && (h2 >= 0) && (h2 < H0);
                uint2 E = make_uint2(0u, 0u);
                uint4 A = make_uint4(0u, 0u, 0u, 0u);
                uint4 B = A, C = A, D = A;
                if (vv) {
                    const u16* rp = base + ((size_t)(d2 * H0 + h2) * W0 + vbase) * 4;
                    A = *(const uint4*)(rp);          // voxels 8q, 8q+1
                    B = *(const uint4*)(rp + 8);      // voxels 8q+2, 8q+3
                    C = *(const uint4*)(rp + 16);     // voxels 8q+4, 8q+5
                    D = *(const uint4*)(rp + 24);     // voxels 8q+6, 8q+7
                    if (q > 0) E = *(const uint2*)(rp - 4);  // voxel 8q-1
                }
                const float* wk = wg + (kd * 9 + kh * 3) * 4;
#pragma unroll
                for (int ci = 0; ci < 4; ++ci) {
                    float e  = SEL2(ci, E.x, E.y);
                    float a0 = SEL2(ci, A.x, A.y), a1 = SEL2(ci, A.z, A.w);
                    float b0 = SEL2(ci, B.x, B.y), b1 = SEL2(ci, B.z, B.w);
                    float c0 = SEL2(ci, C.x, C.y), c1 = SEL2(ci, C.z, C.w);
                    float e0 = SEL2(ci, D.x, D.y), e1 = SEL2(ci, D.z, D.w);
                    const float* wp_ = wk + ci * 108;
                    float4 wA = *(const float4*)(wp_);        // kw=0, m0..3
                    float4 wB = *(const float4*)(wp_ + 4);    // kw=1
                    float4 wC = *(const float4*)(wp_ + 8);    // kw=2
                    acc[0][0] += e  * wA.x + a0 * wB.x + a1 * wC.x;
                    acc[0][1] += e  * wA.y + a0 * wB.y + a1 * wC.y;
                    acc[0][2] += e  * wA.z + a0 * wB.z + a1 * wC.z;
                    acc[0][3] += e  * wA.w + a0 * wB.w + a1 * wC.w;
                    acc[1][0] += a1 * wA.x + b0 * wB.x + b1 * wC.x;
                    acc[1][1] += a1 * wA.y + b0 * wB.y + b1 * wC.y;
                    acc[1][2] += a1 * wA.z + b0 * wB.z + b1 * wC.z;
                    acc[1][3] += a1 * wA.w + b0 * wB.w + b1 * wC.w;
                    acc[2][0] += b1 * wA.x + c0 * wB.x + c1 * wC.x;
                    acc[2][1] += b1 * wA.y + c0 * wB.y + c1 * wC.y;
                    acc[2][2] += b1 * wA.z + c0 * wB.z + c1 * wC.z;
                    acc[2][3] += b1 * wA.w + c0 * wB.w + c1 * wC.w;
                    acc[3][0] += c1 * wA.x + e0 * wB.x + e1 * wC.x;
                    acc[3][1] += c1 * wA.y + e0 * wB.y + e1 * wC.y;
                    acc[3][2] += c1 * wA.z + e0 * wB.z + e1 * wC.z;
                    acc[3][3] += c1 * wA.w + e0 * wB.w + e1 * wC.w;
                    if (kh >= 1 && kd >= 1) {   // kh compile-time; kd wave-uniform
                        mxp[g][ci][0] = fmaxf(mxp[g][ci][0], fmaxf(a0, a1));
                        mxp[g][ci][1] = fmaxf(mxp[g][ci][1], fmaxf(b0, b1));
                        mxp[g][ci][2] = fmaxf(mxp[g][ci][2], fmaxf(c0, c1));
                        mxp[g][ci][3] = fmaxf(mxp[g][ci][3], fmaxf(e0, e1));
                    }
                }
            }
        }
    }
    // Epilogue: one contiguous 256B burst per thread (4 outputs x 64B)
    // + (FUSE_PW) pw 16->4 on the register-resident x1 channels.
#pragma unroll
    for (int j = 0; j < 4; ++j) {
        float x1v[16];
        x1v[0] = fmaxf(acc[j][0], 0.f); x1v[1] = fmaxf(acc[j][1], 0.f);
        x1v[2] = fmaxf(acc[j][2], 0.f); x1v[3] = fmaxf(acc[j][3], 0.f);
#pragma unroll
        for (int g = 0; g < 3; ++g) {
            x1v[4 + 4 * g + 0] = fmaxf(mxp[g][0][j], 0.f);
            x1v[4 + 4 * g + 1] = fmaxf(mxp[g][1][j], 0.f);
            x1v[4 + 4 * g + 2] = fmaxf(mxp[g][2][j], 0.f);
            x1v[4 + 4 * g + 3] = fmaxf(mxp[g][3][j], 0.f);
        }
        float* xo = x1i + (o0 + j) * 16;
        *(float4*)(xo)      = make_float4(x1v[0], x1v[1], x1v[2], x1v[3]);
        *(float4*)(xo + 4)  = make_float4(x1v[4], x1v[5], x1v[6], x1v[7]);
        *(float4*)(xo + 8)  = make_float4(x1v[8], x1v[9], x1v[10], x1v[11]);
        *(float4*)(xo + 12) = make_float4(x1v[12], x1v[13], x1v[14], x1v[15]);
        if (FUSE_PW) {
            float y[4];
#pragma unroll
            for (int m = 0; m < 4; ++m) {
                const float* wm = wpl + m * 16;
                float r = 0.f;
#pragma unroll
                for (int k = 0; k < 16; ++k) r += x1v[k] * wm[k];
                y[m] = fmaxf(r, 0.f);
            }
            *(float4*)(y0o + (o0 + j) * 4) = make_float4(y[0], y[1], y[2], y[3]);
        }
    }
}

// ============================================================
// pw 16->4: x1 interleaved [N1][16] -> y0 interleaved [N1][4], relu
// (smallws fallback path only)
// ============================================================
__global__ void __launch_bounds__(256) kz_pw16to4i(const float* __restrict__ in,
                                                   const float* __restrict__ w,
                                                   float* __restrict__ out) {
    __shared__ float wl[64];
    if (threadIdx.x < 64) wl[threadIdx.x] = w[threadIdx.x];
    __syncthreads();
    int o = blockIdx.x * 256 + threadIdx.x;   // exact
    const float* ip = in + (size_t)o * 16;
    float4 A = *(const float4*)(ip);
    float4 B = *(const float4*)(ip + 4);
    float4 C = *(const float4*)(ip + 8);
    float4 D = *(const float4*)(ip + 12);
    float r[4];
#pragma unroll
    for (int m = 0; m < 4; ++m) {
        const float* wm = wl + m * 16;
        r[m] = A.x * wm[0] + A.y * wm[1] + A.z * wm[2] + A.w * wm[3]
             + B.x * wm[4] + B.y * wm[5] + B.z * wm[6] + B.w * wm[7]
             + C.x * wm[8] + C.y * wm[9] + C.z * wm[10] + C.w * wm[11]
             + D.x * wm[12] + D.y * wm[13] + D.z * wm[14] + D.w * wm[15];
    }
    *(float4*)(out + (size_t)o * 4) = make_float4(fmaxf(r[0], 0.f), fmaxf(r[1], 0.f),
                                                  fmaxf(r[2], 0.f), fmaxf(r[3], 0.f));
}

// ============================================================
// bconv 4ch interleaved [N1][4]: (KD,KH,KW), bias, NADD residuals, relu
// ============================================================
template <int KD, int KH, int KW, int NADD>
__global__ void __launch_bounds__(256) kz_bconv4i(const float* __restrict__ in,
                                                  const float* __restrict__ w,
                                                  const float* __restrict__ b,
                                                  const float* __restrict__ add1,
                                                  const float* __restrict__ add2,
                                                  float* __restrict__ out) {
    constexpr int S = KD * KH * KW;
    __shared__ float wl[16 * S];          // [tap][ci][m]
    __shared__ float bl[4];
    for (int t = threadIdx.x; t < 16 * S; t += 256) {
        int m = t & 3;
        int r = t >> 2;      // tap*4 + ci
        int ci = r & 3;
        int tap = r >> 2;
        wl[t] = w[(m * 4 + ci) * S + tap];
    }
    if (threadIdx.x < 4) bl[threadIdx.x] = b[threadIdx.x];
    __syncthreads();
    int o = blockIdx.x * 256 + threadIdx.x;   // exact: N1/256
    int wo = o % W1;
    int t  = o / W1;
    int ho = t % H1;
    int d0 = t / H1;
    float a0 = bl[0], a1 = bl[1], a2 = bl[2], a3 = bl[3];
#pragma unroll
    for (int kd = 0; kd < KD; ++kd) {
        int d2 = d0 + kd - KD / 2;
        if (KD > 1 && (d2 < 0 || d2 >= D1)) continue;
#pragma unroll
        for (int kh = 0; kh < KH; ++kh) {
            int h2 = ho + kh - KH / 2;
            if (KH > 1 && (h2 < 0 || h2 >= H1)) continue;
#pragma unroll
            for (int kw = 0; kw < KW; ++kw) {
                int w2 = wo + kw - KW / 2;
                if (KW > 1 && (w2 < 0 || w2 >= W1)) continue;
                float4 v = *(const float4*)(in + (size_t)((d2 * H1 + h2) * W1 + w2) * 4);
                int tap = (kd * KH + kh) * KW + kw;
                const float* wt = wl + tap * 16;
                float4 w0 = *(const float4*)(wt);
                float4 w1 = *(const float4*)(wt + 4);
                float4 w2v = *(const float4*)(wt + 8);
                float4 w3 = *(const float4*)(wt + 12);
                a0 += v.x * w0.x + v.y * w1.x + v.z * w2v.x + v.w * w3.x;
                a1 += v.x * w0.y + v.y * w1.y + v.z * w2v.y + v.w * w3.y;
                a2 += v.x * w0.z + v.y * w1.z + v.z * w2v.z + v.w * w3.z;
                a3 += v.x * w0.w + v.y * w1.w + v.z * w2v.w + v.w * w3.w;
            }
        }
    }
    if (NADD >= 1) {
        float4 r1 = *(const float4*)(add1 + (size_t)o * 4);
        a0 += r1.x; a1 += r1.y; a2 += r1.z; a3 += r1.w;
    }
    if (NADD >= 2) {
        float4 r2 = *(const float4*)(add2 + (size_t)o * 4);
        a0 += r2.x; a1 += r2.y; a2 += r2.z; a3 += r2.w;
    }
    *(float4*)(out + (size_t)o * 4) = make_float4(fmaxf(a0, 0.f), fmaxf(a1, 0.f),
                                                  fmaxf(a2, 0.f), fmaxf(a3, 0.f));
}

// ============================================================
// FUSED: bconv4 (3,1,3) + bias + 2 residuals + relu -> pw 4->16
//        + residual(x1i) + relu -> x1b PLANAR [16][N1]
// ============================================================
__global__ void __launch_bounds__(256) kz_bconv4i_pw(const float* __restrict__ in,
                                                     const float* __restrict__ w,
                                                     const float* __restrict__ b,
                                                     const float* __restrict__ add1,
                                                     const float* __restrict__ add2,
                                                     const float* __restrict__ wp,
                                                     const float* __restrict__ x1i,
                                                     float* __restrict__ out) {
    constexpr int S = 9;   // 3*1*3
    __shared__ float wl[16 * S];          // [tap][ci][m]
    __shared__ float bl[4];
    __shared__ float wpl[64];
    for (int t = threadIdx.x; t < 16 * S; t += 256) {
        int m = t & 3;
        int r = t >> 2;
        int ci = r & 3;
        int tap = r >> 2;
        wl[t] = w[(m * 4 + ci) * S + tap];
    }
    if (threadIdx.x < 4) bl[threadIdx.x] = b[threadIdx.x];
    if (threadIdx.x < 64) wpl[threadIdx.x] = wp[threadIdx.x];
    __syncthreads();
    int o = blockIdx.x * 256 + threadIdx.x;   // exact
    int wo = o % W1;
    int t  = o / W1;
    int ho = t % H1;
    int d0 = t / H1;
    float a0 = bl[0], a1 = bl[1], a2 = bl[2], a3 = bl[3];
#pragma unroll
    for (int kd = 0; kd < 3; ++kd) {
        int d2 = d0 + kd - 1;
        if (d2 < 0 || d2 >= D1) continue;
#pragma unroll
        for (int kw = 0; kw < 3; ++kw) {
            int w2 = wo + kw - 1;
            if (w2 < 0 || w2 >= W1) continue;
            float4 v = *(const float4*)(in + (size_t)((d2 * H1 + ho) * W1 + w2) * 4);
            int tap = kd * 3 + kw;
            const float* wt = wl + tap * 16;
            float4 w0 = *(const float4*)(wt);
            float4 w1 = *(const float4*)(wt + 4);
            float4 w2v = *(const float4*)(wt + 8);
            float4 w3 = *(const float4*)(wt + 12);
            a0 += v.x * w0.x + v.y * w1.x + v.z * w2v.x + v.w * w3.x;
            a1 += v.x * w0.y + v.y * w1.y + v.z * w2v.y + v.w * w3.y;
            a2 += v.x * w0.z + v.y * w1.z + v.z * w2v.z + v.w * w3.z;
            a3 += v.x * w0.w + v.y * w1.w + v.z * w2v.w + v.w * w3.w;
        }
    }
    float4 r1 = *(const float4*)(add1 + (size_t)o * 4);
    float4 r2 = *(const float4*)(add2 + (size_t)o * 4);
    float y0 = fmaxf(a0 + r1.x + r2.x, 0.f);
    float y1 = fmaxf(a1 + r1.y + r2.y, 0.f);
    float y2 = fmaxf(a2 + r1.z + r2.z, 0.f);
    float y3 = fmaxf(a3 + r1.w + r2.w, 0.f);
    const float* rp = x1i + (size_t)o * 16;
    float4 R0 = *(const float4*)(rp);
    float4 R1 = *(const float4*)(rp + 4);
    float4 R2 = *(const float4*)(rp + 8);
    float4 R3 = *(const float4*)(rp + 12);
    float rr[16] = {R0.x, R0.y, R0.z, R0.w, R1.x, R1.y, R1.z, R1.w,
                    R2.x, R2.y, R2.z, R2.w, R3.x, R3.y, R3.z, R3.w};
#pragma unroll
    for (int m = 0; m < 16; ++m) {
        const float* wm = wpl + m * 4;
        float r = y0 * wm[0] + y1 * wm[1] + y2 * wm[2] + y3 * wm[3] + rr[m];
        out[(size_t)m * N1 + o] = fmaxf(r, 0.f);
    }
}

// ============================================================
// FUSED Downsample 2 + pw 32->8
// ============================================================
__global__ void __launch_bounds__(256) kz_ds2f(const float* __restrict__ in,
                                               const float* __restrict__ w,
                                               const float* __restrict__ wz,
                                               float* __restrict__ out,
                                               float* __restrict__ z0i) {
    __shared__ float wl[16 * 27 * 16];    // [ci][tap][m] transposed, 27648 B
    __shared__ float wzl[256];            // [k][m] transposed
    for (int t = threadIdx.x; t < 16 * 27 * 16; t += 256) {
        int m = t & 15;
        int r = t >> 4;          // ci*27 + tap
        int tap = r % 27;
        int ci = r / 27;
        wl[t] = w[(m * 16 + ci) * 27 + tap];
    }
    if (threadIdx.x < 256) {
        int m = threadIdx.x & 7;
        int k = threadIdx.x >> 3;
        wzl[threadIdx.x] = wz[m * 32 + k];
    }
    __syncthreads();
    int o = blockIdx.x * 256 + threadIdx.x;
    if (o >= N2) return;
    int wo = o % W2;
    int t  = o / W2;
    int ho = t % H2;
    int d0 = t / H2;
    float acc[16];
    float zacc[8];
#pragma unroll
    for (int m = 0; m < 16; ++m) acc[m] = 0.f;
#pragma unroll
    for (int m = 0; m < 8; ++m) zacc[m] = 0.f;
#pragma unroll 1
    for (int ci = 0; ci < 16; ++ci) {
        const float* base = in + ci * N1;
        const float* wci = wl + ci * 432;   // 27*16
        float mx = -1e30f;
#pragma unroll 1
        for (int kd = 0; kd < 3; ++kd) {
            int d2 = 2 * d0 - 1 + kd;
            bool dv = (d2 >= 0 && d2 < D1);
#pragma unroll
            for (int kh = 0; kh < 3; ++kh) {
                int h2 = 2 * ho - 1 + kh;
                bool rvv = dv && (h2 >= 0 && h2 < H1);
                float vm1 = 0.f, v0 = 0.f, v1 = 0.f;
                if (rvv) {
                    int r2 = (d2 * H1 + h2) * W1 + 2 * wo;
                    float2 pb = *(const float2*)(base + r2);
                    v0 = pb.x; v1 = pb.y;
                    if (wo > 0) {
                        float2 pa = *(const float2*)(base + r2 - 2);
                        vm1 = pa.y;
                    }
                }
                const float* wk = wci + (kd * 9 + kh * 3) * 16;
#pragma unroll
                for (int q = 0; q < 4; ++q) {
                    float4 wA = *(const float4*)(wk + q * 4);        // kw=0
                    float4 wB = *(const float4*)(wk + 16 + q * 4);   // kw=1
                    float4 wC = *(const float4*)(wk + 32 + q * 4);   // kw=2
                    acc[4 * q + 0] += vm1 * wA.x + v0 * wB.x + v1 * wC.x;
                    acc[4 * q + 1] += vm1 * wA.y + v0 * wB.y + v1 * wC.y;
                    acc[4 * q + 2] += vm1 * wA.z + v0 * wB.z + v1 * wC.z;
                    acc[4 * q + 3] += vm1 * wA.w + v0 * wB.w + v1 * wC.w;
                }
                if (kd >= 1 && kh >= 1) mx = fmaxf(mx, fmaxf(v0, v1));
            }
        }
        float pl = fmaxf(mx, 0.f);
        out[(16 + ci) * N2 + o] = pl;
        {
            const float* wq = wzl + (16 + ci) * 8;
            float4 z0 = *(const float4*)(wq);
            float4 z1 = *(const float4*)(wq + 4);
            zacc[0] += z0.x * pl; zacc[1] += z0.y * pl; zacc[2] += z0.z * pl; zacc[3] += z0.w * pl;
            zacc[4] += z1.x * pl; zacc[5] += z1.y * pl; zacc[6] += z1.z * pl; zacc[7] += z1.w * pl;
        }
    }
#pragma unroll
    for (int j = 0; j < 16; ++j) {
        float cj = fmaxf(acc[j], 0.f);
        out[j * N2 + o] = cj;
        const float* wq = wzl + j * 8;
        float4 z0 = *(const float4*)(wq);
        float4 z1 = *(const float4*)(wq + 4);
        zacc[0] += z0.x * cj; zacc[1] += z0.y * cj; zacc[2] += z0.z * cj; zacc[3] += z0.w * cj;
        zacc[4] += z1.x * cj; zacc[5] += z1.y * cj; zacc[6] += z1.z * cj; zacc[7] += z1.w * cj;
    }
    float* op = z0i + (size_t)o * 8;
    *(float4*)(op)     = make_float4(fmaxf(zacc[0], 0.f), fmaxf(zacc[1], 0.f),
                                     fmaxf(zacc[2], 0.f), fmaxf(zacc[3], 0.f));
    *(float4*)(op + 4) = make_float4(fmaxf(zacc[4], 0.f), fmaxf(zacc[5], 0.f),
                                     fmaxf(zacc[6], 0.f), fmaxf(zacc[7], 0.f));
}

// ============================================================
// bconv 8ch interleaved [N2][8]
// ============================================================
template <int KD, int KH, int KW, int NADD>
__global__ void __launch_bounds__(256) kz_bconv8i(const float* __restrict__ in,
                                                  const float* __restrict__ w,
                                                  const float* __restrict__ b,
                                                  const float* __restrict__ add1,
                                                  const float* __restrict__ add2,
                                                  float* __restrict__ out) {
    constexpr int S = KD * KH * KW;
    __shared__ float wl[64 * S];          // [tap][ci][m]
    __shared__ float bl[8];
    for (int t = threadIdx.x; t < 64 * S; t += 256) {
        int m = t & 7;
        int r = t >> 3;      // tap*8 + ci
        int ci = r & 7;
        int tap = r >> 3;
        wl[t] = w[(m * 8 + ci) * S + tap];
    }
    if (threadIdx.x < 8) bl[threadIdx.x] = b[threadIdx.x];
    __syncthreads();
    int o = blockIdx.x * 256 + threadIdx.x;
    if (o >= N2) return;
    int wo = o % W2;
    int t  = o / W2;
    int ho = t % H2;
    int d0 = t / H2;
    float acc[8];
#pragma unroll
    for (int m = 0; m < 8; ++m) acc[m] = bl[m];
#pragma unroll
    for (int kd = 0; kd < KD; ++kd) {
        int d2 = d0 + kd - KD / 2;
        if (KD > 1 && (d2 < 0 || d2 >= D2)) continue;
#pragma unroll
        for (int kh = 0; kh < KH; ++kh) {
            int h2 = ho + kh - KH / 2;
            if (KH > 1 && (h2 < 0 || h2 >= H2)) continue;
#pragma unroll
            for (int kw = 0; kw < KW; ++kw) {
                int w2 = wo + kw - KW / 2;
                if (KW > 1 && (w2 < 0 || w2 >= W2)) continue;
                const float* vp = in + (size_t)((d2 * H2 + h2) * W2 + w2) * 8;
                float4 v0 = *(const float4*)(vp);
                float4 v1 = *(const float4*)(vp + 4);
                float vv[8] = {v0.x, v0.y, v0.z, v0.w, v1.x, v1.y, v1.z, v1.w};
                int tap = (kd * KH + kh) * KW + kw;
                const float* wt = wl + tap * 64;
#pragma unroll
                for (int ci = 0; ci < 8; ++ci) {
                    float vc = vv[ci];
                    float4 wa = *(const float4*)(wt + ci * 8);
                    float4 wb = *(const float4*)(wt + ci * 8 + 4);
                    acc[0] += vc * wa.x; acc[1] += vc * wa.y;
                    acc[2] += vc * wa.z; acc[3] += vc * wa.w;
                    acc[4] += vc * wb.x; acc[5] += vc * wb.y;
                    acc[6] += vc * wb.z; acc[7] += vc * wb.w;
                }
            }
        }
    }
    if (NADD >= 1) {
        const float* ap = add1 + (size_t)o * 8;
        float4 r0 = *(const float4*)(ap), r1 = *(const float4*)(ap + 4);
        acc[0] += r0.x; acc[1] += r0.y; acc[2] += r0.z; acc[3] += r0.w;
        acc[4] += r1.x; acc[5] += r1.y; acc[6] += r1.z; acc[7] += r1.w;
    }
    if (NADD >= 2) {
        const float* ap = add2 + (size_t)o * 8;
        float4 r0 = *(const float4*)(ap), r1 = *(const float4*)(ap + 4);
        acc[0] += r0.x; acc[1] += r0.y; acc[2] += r0.z; acc[3] += r0.w;
        acc[4] += r1.x; acc[5] += r1.y; acc[6] += r1.z; acc[7] += r1.w;
    }
    float* op = out + (size_t)o * 8;
    *(float4*)(op)     = make_float4(fmaxf(acc[0], 0.f), fmaxf(acc[1], 0.f),
                                     fmaxf(acc[2], 0.f), fmaxf(acc[3], 0.f));
    *(float4*)(op + 4) = make_float4(fmaxf(acc[4], 0.f), fmaxf(acc[5], 0.f),
                                     fmaxf(acc[6], 0.f), fmaxf(acc[7], 0.f));
}

// ============================================================
// FUSED: bconv8 (3,1,3) + residuals + relu -> pw 8->32 + residual + relu
// -> d_out planar [32][N2]
// ============================================================
__global__ void __launch_bounds__(256) kz_bconv8i_pw(const float* __restrict__ in,
                                                     const float* __restrict__ w,
                                                     const float* __restrict__ b,
                                                     const float* __restrict__ add1,
                                                     const float* __restrict__ add2,
                                                     const float* __restrict__ wp,
                                                     const float* __restrict__ resp,
                                                     float* __restrict__ out) {
    constexpr int S = 9;   // 3*1*3
    __shared__ float wl[64 * S];          // [tap][ci][m]
    __shared__ float bl[8];
    __shared__ float wpl[256];
    for (int t = threadIdx.x; t < 64 * S; t += 256) {
        int m = t & 7;
        int r = t >> 3;
        int ci = r & 7;
        int tap = r >> 3;
        wl[t] = w[(m * 8 + ci) * S + tap];
    }
    if (threadIdx.x < 8) bl[threadIdx.x] = b[threadIdx.x];
    if (threadIdx.x < 256) wpl[threadIdx.x] = wp[threadIdx.x];
    __syncthreads();
    int o = blockIdx.x * 256 + threadIdx.x;
    if (o >= N2) return;
    int wo = o % W2;
    int t  = o / W2;
    int ho = t % H2;
    int d0 = t / H2;
    float acc[8];
#pragma unroll
    for (int m = 0; m < 8; ++m) acc[m] = bl[m];
#pragma unroll
    for (int kd = 0; kd < 3; ++kd) {
        int d2 = d0 + kd - 1;
        if (d2 < 0 || d2 >= D2) continue;
#pragma unroll
        for (int kw = 0; kw < 3; ++kw) {
            int w2 = wo + kw - 1;
            if (w2 < 0 || w2 >= W2) continue;
            const float* vp = in + (size_t)((d2 * H2 + ho) * W2 + w2) * 8;
            float4 v0 = *(const float4*)(vp);
            float4 v1 = *(const float4*)(vp + 4);
            float vv[8] = {v0.x, v0.y, v0.z, v0.w, v1.x, v1.y, v1.z, v1.w};
            int tap = kd * 3 + kw;
            const float* wt = wl + tap * 64;
#pragma unroll
            for (int ci = 0; ci < 8; ++ci) {
                float vc = vv[ci];
                float4 wa = *(const float4*)(wt + ci * 8);
                float4 wb = *(const float4*)(wt + ci * 8 + 4);
                acc[0] += vc * wa.x; acc[1] += vc * wa.y;
                acc[2] += vc * wa.z; acc[3] += vc * wa.w;
                acc[4] += vc * wb.x; acc[5] += vc * wb.y;
                acc[6] += vc * wb.z; acc[7] += vc * wb.w;
            }
        }
    }
    {
        const float* ap = add1 + (size_t)o * 8;
        float4 r0 = *(const float4*)(ap), r1 = *(const float4*)(ap + 4);
        acc[0] += r0.x; acc[1] += r0.y; acc[2] += r0.z; acc[3] += r0.w;
        acc[4] += r1.x; acc[5] += r1.y; acc[6] += r1.z; acc[7] += r1.w;
    }
    {
        const float* ap = add2 + (size_t)o * 8;
        float4 r0 = *(const float4*)(ap), r1 = *(const float4*)(ap + 4);
        acc[0] += r0.x; acc[1] += r0.y; acc[2] += r0.z; acc[3] += r0.w;
        acc[4] += r1.x; acc[5] += r1.y; acc[6] += r1.z; acc[7] += r1.w;
    }
#pragma unroll
    for (int m = 0; m < 8; ++m) acc[m] = fmaxf(acc[m], 0.f);
#pragma unroll
    for (int m = 0; m < 32; ++m) {
        const float* wm = wpl + m * 8;
        float r = acc[0] * wm[0] + acc[1] * wm[1] + acc[2] * wm[2] + acc[3] * wm[3]
                + acc[4] * wm[4] + acc[5] * wm[5] + acc[6] * wm[6] + acc[7] * wm[7];
        r += resp[(size_t)m * N2 + o];
        out[(size_t)m * N2 + o] = fmaxf(r, 0.f);
    }
}

// ============================================================
extern "C" void kernel_launch(void* const* d_in, const int* in_sizes, int n_in,
                              void* d_out, int out_size, void* d_ws, size_t ws_size,
                              hipStream_t stream) {
    const float* feat   = (const float*)d_in[0];
    const int*   depth  = (const int*)d_in[1];
    const float* w_ds1  = (const float*)d_in[2];
    const float* b1_win = (const float*)d_in[3];
    const float* b1w133 = (const float*)d_in[4];
    const float* b1b133 = (const float*)d_in[5];
    const float* b1w331 = (const float*)d_in[6];
    const float* b1b331 = (const float*)d_in[7];
    const float* b1w313 = (const float*)d_in[8];
    const float* b1b313 = (const float*)d_in[9];
    const float* b1wout = (const float*)d_in[10];
    const float* w_ds2  = (const float*)d_in[11];
    const float* b2_win = (const float*)d_in[12];
    const float* b2w133 = (const float*)d_in[13];
    const float* b2b133 = (const float*)d_in[14];
    const float* b2w331 = (const float*)d_in[15];
    const float* b2b331 = (const float*)d_in[16];
    const float* b2w313 = (const float*)d_in[17];
    const float* b2b313 = (const float*)d_in[18];
    const float* b2wout = (const float*)d_in[19];

    char* base = (char*)d_ws;
    // Branch once on ws_size (deterministic every call -> graph-safe).
    const bool bigws = (ws_size >= BIG_WS);

    // --- Region layout ---
    u16* raw0 = (u16*)base;                               // [0, 66.35)
    u16* raw1 = (u16*)(base + GRP_BYTES);                 // [66.35, 132.7)
    u16* raw2 = (u16*)(base + 2 * GRP_BYTES);             // [132.7, 199.07)
    unsigned* winner = (unsigned*)(base + SEG_BYTES);     // [199.07, 232.25)
    u16* fil0 = bigws ? (u16*)(base + SEG_BYTES + WIN_BYTES) : (u16*)(base + SEG_BYTES);
    u16* fil1 = (u16*)base;                               // [0, 66.35)   after raw0 dies
    u16* fil2 = (u16*)(base + GRP_BYTES);                 // [66.35,132.7) after raw1 dies
    float* x1i = (float*)(base + 2 * GRP_BYTES);          // [132.7,199.07) after raw2 dies
    // y-chain: bigws -> y0 in dead winner region (so ds1 can write it while
    //          fil1/fil2 @ base are still being read); y1/y2 at base after
    //          fils die. smallws -> R13 layout (separate pw kernel).
    float* y0i = bigws ? (float*)(base + SEG_BYTES) : (float*)base;
    float* y1i = bigws ? (float*)base : (float*)base + 4 * N1;
    float* y2i = y1i + 4 * N1;
    float* x1b = (float*)(base + SEG_BYTES);              // [199.07,265.4) (winner/y0 dead)
    float* x2  = (float*)base;                            // after y dead
    float* z0i = x2 + 32 * N2;
    float* z1i = z0i + 8 * N2;
    float* z2i = z1i + 8 * N2;

    float* out = (float*)d_out;   // reference output dtype is float32

    // 1. zero
    if (bigws) {
        kz_zero16<<<WCHUNKS / 256, 256, 0, stream>>>((uint4*)winner, WCHUNKS);
    } else {
        kz_zero16<<<ZCHUNKS / 256, 256, 0, stream>>>((uint4*)base, ZCHUNKS);
    }

    // 2. deterministic last-write-wins scatter
    kz_scatter_win  <<<NPIX / 256, 256, 0, stream>>>(depth, winner);
    kz_scatter_write<<<NPIX / 256, 256, 0, stream>>>(depth, winner, feat, raw0);

    // 3. one-pass LDS-shared hole-fill, per group, out-of-place (rotating)
    if (bigws) {
        kz_fillL<true><<<4320, 256, 0, stream>>>(raw0, winner, fil0);
        kz_fillL<true><<<4320, 256, 0, stream>>>(raw1, winner, fil1);
        kz_fillL<true><<<4320, 256, 0, stream>>>(raw2, winner, fil2);
    } else {
        kz_fillL<false><<<4320, 256, 0, stream>>>(raw0, nullptr, fil0);
        kz_fillL<false><<<4320, 256, 0, stream>>>(raw1, nullptr, fil1);
        kz_fillL<false><<<4320, 256, 0, stream>>>(raw2, nullptr, fil2);
    }

    // 4. downsample 1 (W-pack x4; bigws: fused pw16->4 epilogue)
    if (bigws) {
        kz_ds1<true><<<(N1 / 4 + 255) / 256, 256, 0, stream>>>(fil0, fil1, fil2, w_ds1,
                                                               b1_win, x1i, y0i);
    } else {
        kz_ds1<false><<<(N1 / 4 + 255) / 256, 256, 0, stream>>>(fil0, fil1, fil2, w_ds1,
                                                                nullptr, x1i, nullptr);
        kz_pw16to4i<<<N1 / 256, 256, 0, stream>>>(x1i, b1_win, y0i);
    }

    // 5. bottleneck 1 (interleaved [N1][4]); last bconv fused with pw4->16
    kz_bconv4i<1, 3, 3, 0><<<N1 / 256, 256, 0, stream>>>(y0i, b1w133, b1b133, nullptr, nullptr, y1i);
    kz_bconv4i<3, 3, 1, 1><<<N1 / 256, 256, 0, stream>>>(y1i, b1w331, b1b331, y1i, nullptr, y2i);
    kz_bconv4i_pw<<<N1 / 256, 256, 0, stream>>>(y2i, b1w313, b1b313, y2i, y1i, b1wout, x1i, x1b);

    // 6. downsample 2 fused with pw32->8 -> x2 planar + z0 interleaved
    kz_ds2f<<<(N2 + 255) / 256, 256, 0, stream>>>(x1b, w_ds2, b2_win, x2, z0i);

    // 7. bottleneck 2 (interleaved [N2][8]); last bconv fused with pw8->32
    kz_bconv8i<1, 3, 3, 0><<<(N2 + 255) / 256, 256, 0, stream>>>(z0i, b2w133, b2b133, nullptr, nullptr, z1i);
    kz_bconv8i<3, 3, 1, 1><<<(N2 + 255) / 256, 256, 0, stream>>>(z1i, b2w331, b2b331, z1i, nullptr, z2i);
    kz_bconv8i_pw<<<(N2 + 255) / 256, 256, 0, stream>>>(z2i, b2w313, b2b313, z2i, z1i, b2wout, x2, out);

    (void)in_sizes; (void)n_in; (void)out_size;
}